// Round 18
// baseline (474.805 us; speedup 1.0000x reference)
//
#include <hip/hip_runtime.h>
#include <hip/hip_bf16.h>
#include <math.h>

#define B_ 2
#define T_ 2048
#define C_ 4096
#define NH_ 32
#define NKV_ 8
#define HD_ 128
#define M_ (B_*T_)              // 4096 rows
#define QKVN_ (NH_*HD_ + 2*NKV_*HD_)  // 6144

using bf16 = __hip_bfloat16;
typedef __bf16 bf16x8 __attribute__((ext_vector_type(8)));
typedef float f32x4 __attribute__((ext_vector_type(4)));

__device__ inline f32x4 mfma16(bf16x8 a, bf16x8 b, f32x4 c) {
    return __builtin_amdgcn_mfma_f32_16x16x32_bf16(a, b, c, 0, 0, 0);
}

// ---------------- cast f32 -> bf16 (vectorized x4) ----------------
__global__ __launch_bounds__(256) void cast_f32_bf16(const float* __restrict__ in,
                                                     bf16* __restrict__ out, int n4) {
    int i = blockIdx.x * 256 + threadIdx.x;
    if (i >= n4) return;
    float4 v = reinterpret_cast<const float4*>(in)[i];
    union { bf16 h[4]; uint2 u; } o;
    o.h[0] = __float2bfloat16(v.x);
    o.h[1] = __float2bfloat16(v.y);
    o.h[2] = __float2bfloat16(v.z);
    o.h[3] = __float2bfloat16(v.w);
    reinterpret_cast<uint2*>(out)[i] = o.u;
}

// ---------------- transpose + cast: in f32 [K][N] -> out bf16 [N][K] ----------------
__global__ __launch_bounds__(256) void transpose_cast(const float* __restrict__ in,
                                                      bf16* __restrict__ out, int K, int N) {
    __shared__ float tile[32][33];
    int tx = threadIdx.x & 31, ty = threadIdx.x >> 5;  // 32 x 8
    int n0 = blockIdx.x << 5, k0 = blockIdx.y << 5;
#pragma unroll
    for (int p = 0; p < 4; ++p)
        tile[p*8 + ty][tx] = in[(size_t)(k0 + p*8 + ty) * N + n0 + tx];
    __syncthreads();
#pragma unroll
    for (int p = 0; p < 4; ++p)
        out[(size_t)(n0 + p*8 + ty) * K + k0 + tx] = __float2bfloat16(tile[tx][p*8 + ty]);
}

// ---------------- fused wq|wk|wv transpose: 3 srcs -> wqkvT [6144][4096] ----------------
__global__ __launch_bounds__(256) void transpose_cast3(const float* __restrict__ wq,
                                                       const float* __restrict__ wk,
                                                       const float* __restrict__ wv,
                                                       bf16* __restrict__ out, int K) {
    __shared__ float tile[32][33];
    int tx = threadIdx.x & 31, ty = threadIdx.x >> 5;  // 32 x 8
    int nt = blockIdx.x, k0 = blockIdx.y << 5;
    const float* src; int N, nloc;
    if (nt < 128)      { src = wq; N = 4096; nloc = nt << 5; }
    else if (nt < 160) { src = wk; N = 1024; nloc = (nt - 128) << 5; }
    else               { src = wv; N = 1024; nloc = (nt - 160) << 5; }
#pragma unroll
    for (int p = 0; p < 4; ++p)
        tile[p*8 + ty][tx] = src[(size_t)(k0 + p*8 + ty) * N + nloc + tx];
    __syncthreads();
    int nglob = nt << 5;
#pragma unroll
    for (int p = 0; p < 4; ++p)
        out[(size_t)(nglob + p*8 + ty) * K + k0 + tx] = __float2bfloat16(tile[tx][p*8 + ty]);
}

// ---------------- RoPE cos/sin table ----------------
__global__ __launch_bounds__(256) void rope_tab(float2* __restrict__ tab) {
    int idx = blockIdx.x * 256 + threadIdx.x;   // t*64 + i
    int i = idx & 63, t = idx >> 6;
    float inv = exp2f((float)i * -0.20762050593045952f);
    float th = (float)t * inv;
    tab[idx] = make_float2(cosf(th), sinf(th));
}

// ======== shared GEMM phase machinery (256x256, BK=64, 8 waves, 8-phase) ========
// R14-proven schedule (register ceiling: do not add operand registers).
#define GEMM_PROLOG_AND_LOOP(TAG)                                                       \
    f32x4 acc[8][4] = {};                                                               \
    bf16x8 a[4][2], b0[2][2], b1[2][2];                                                 \
    STAGE_HALF(Ag, 0,     0, 0, 0); STAGE_HALF(Ag, 0,     0, 0, 1);                     \
    STAGE_HALF(Bg, 65536, 0, 0, 0); STAGE_HALF(Bg, 65536, 0, 0, 1);                     \
    STAGE_HALF(Bg, 65536, 1, 1, 0); STAGE_HALF(Bg, 65536, 1, 1, 1);                     \
    asm volatile("s_waitcnt vmcnt(4)" ::: "memory");                                    \
    BAR();                                                                              \
    for (int it = 0; it < (nt >> 1); ++it) {                                            \
        const int u = 2 * it;                                                           \
        const bool more = (u + 2) < nt;                                                 \
        const bool more3 = (u + 3) < nt;                                                \
        READ_A(0, 0); READ_B(0, 0, b0);                                                 \
        STAGE_HALF(Ag, 0, u + 1, 1, 0);                                                 \
        MFMA_Q(0, 0, b0);                                                               \
        BAR();                                                                          \
        READ_B(0, 1, b1);                                                               \
        STAGE_HALF(Ag, 0, u + 1, 1, 1);                                                 \
        MFMA_Q(0, 2, b1);                                                               \
        BAR();                                                                          \
        READ_A(0, 1);                                                                   \
        if (more) STAGE_HALF(Bg, 65536, u + 2, 0, 0);                                   \
        MFMA_Q(4, 2, b1);                                                               \
        BAR();                                                                          \
        if (more) STAGE_HALF(Bg, 65536, u + 2, 0, 1);                                   \
        MFMA_Q(4, 0, b0);                                                               \
        if (more) asm volatile("s_waitcnt vmcnt(8)" ::: "memory");                      \
        else      asm volatile("s_waitcnt vmcnt(4)" ::: "memory");                      \
        BAR();                                                                          \
        READ_A(1, 0); READ_B(1, 0, b0);                                                 \
        if (more) STAGE_HALF(Ag, 0, u + 2, 0, 0);                                       \
        MFMA_Q(0, 0, b0);                                                               \
        BAR();                                                                          \
        READ_B(1, 1, b1);                                                               \
        if (more) STAGE_HALF(Ag, 0, u + 2, 0, 1);                                       \
        MFMA_Q(0, 2, b1);                                                               \
        if (more) asm volatile("s_waitcnt vmcnt(8)" ::: "memory");                      \
        else      asm volatile("s_waitcnt vmcnt(0)" ::: "memory");                      \
        BAR();                                                                          \
        READ_A(1, 1);                                                                   \
        if (more3) STAGE_HALF(Bg, 65536, u + 3, 1, 0);                                  \
        MFMA_Q(4, 2, b1);                                                               \
        BAR();                                                                          \
        if (more3) STAGE_HALF(Bg, 65536, u + 3, 1, 1);                                  \
        MFMA_Q(4, 0, b0);                                                               \
        if (more3) asm volatile("s_waitcnt vmcnt(4)" ::: "memory");                     \
        else       asm volatile("s_waitcnt vmcnt(0)" ::: "memory");                     \
        BAR();                                                                          \
    }

#define GEMM_COMMON_DEFS                                                                \
    const int tid = threadIdx.x;                                                        \
    const int wid = tid >> 6, lane = tid & 63;                                          \
    const int lq = lane & 15, lg = lane >> 4;                                           \
    const int wrow = wid >> 2, wcol = wid & 3;                                          \
    const int nwg = gridDim.x;                                                          \
    const int q8 = nwg >> 3;                                                            \
    const int wg = (blockIdx.x & 7) * q8 + (blockIdx.x >> 3);                           \
    const int srow = (wid << 3) + (lane >> 3);                                          \
    const int schunk = (lane & 7) ^ ((lane >> 3) & 7);

#define STAGE_HALF(gbase, ldsoff, t2, cbuf, hf)                                         \
    {                                                                                   \
        _Pragma("unroll")                                                               \
        for (int l = 0; l < 2; ++l) {                                                   \
            const int r0 = (hf) * 128 + l * 64;                                         \
            const char* src = (const char*)(gbase) +                                    \
                ((size_t)(r0 + srow) * K + (size_t)(t2) * 64) * 2 + schunk * 16;        \
            char* dst = &lds[(ldsoff) + (cbuf) * 32768 + (r0 + (wid << 3)) * 128];      \
            __builtin_amdgcn_global_load_lds(                                           \
                (const __attribute__((address_space(1))) void*)src,                     \
                (__attribute__((address_space(3))) void*)dst, 16, 0, 0);                \
        }                                                                               \
    }

#define LDA(cbuf, mh, mf, ks) \
    (*(const bf16x8*)&lds[(cbuf)*32768 + (wrow*128 + (mh)*64 + (mf)*16 + lq)*128 + ((((ks)*4 + lg)) ^ (lq & 7))*16])

#define READ_A(cbuf, mh) \
    { _Pragma("unroll") for (int mf = 0; mf < 4; ++mf) { a[mf][0] = LDA(cbuf, mh, mf, 0); a[mf][1] = LDA(cbuf, mh, mf, 1); } }
#define READ_B(cbuf, nh, breg) \
    { _Pragma("unroll") for (int nf = 0; nf < 2; ++nf) { breg[nf][0] = LDB(cbuf, nh, nf, 0); breg[nf][1] = LDB(cbuf, nh, nf, 1); } }
#define MFMA_Q(am, an, breg)                                                     \
    { __builtin_amdgcn_s_setprio(1);                                             \
      _Pragma("unroll") for (int mf = 0; mf < 4; ++mf)                           \
          _Pragma("unroll") for (int nf = 0; nf < 2; ++nf)                       \
              _Pragma("unroll") for (int ks = 0; ks < 2; ++ks)                   \
                  acc[(am) + mf][(an) + nf] = mfma16(a[mf][ks], breg[nf][ks],    \
                                                     acc[(am) + mf][(an) + nf]); \
      __builtin_amdgcn_s_setprio(0); }
#define BAR() __builtin_amdgcn_s_barrier()

// ---------------- plain 256x256 GEMM (out-proj): C[M][N] = A @ Bt^T ----------------
__device__ inline void store_out(float* p, float v) { *p = v; }
__device__ inline void store_out(bf16*  p, float v) { *p = __float2bfloat16(v); }

template <typename OutT>
__global__ __launch_bounds__(512, 2) void gemm256(const bf16* __restrict__ A,
                                                  const bf16* __restrict__ Bt,
                                                  OutT* __restrict__ C,
                                                  int M, int N, int K) {
    __shared__ __align__(16) char lds[131072];
    GEMM_COMMON_DEFS
    const int nby = M >> 8;
    const int by = wg % nby, bx = wg / nby;
    const int brow = by << 8, bcol = bx << 8;
    const bf16* Ag = A + (size_t)brow * K;
    const bf16* Bg = Bt + (size_t)bcol * K;
    const int nt = K >> 6;
#define LDB(cbuf, nh, nf, ks) \
    (*(const bf16x8*)&lds[65536 + (cbuf)*32768 + (wcol*64 + (nh)*32 + (nf)*16 + lq)*128 + ((((ks)*4 + lg)) ^ (lq & 7))*16])
    GEMM_PROLOG_AND_LOOP(plain)
#undef LDB
#pragma unroll
    for (int mf = 0; mf < 8; ++mf)
#pragma unroll
        for (int nf = 0; nf < 4; ++nf)
#pragma unroll
            for (int r = 0; r < 4; ++r) {
                int row = brow + wrow * 128 + mf * 16 + lg * 4 + r;
                int col = bcol + wcol * 64 + nf * 16 + lq;
                store_out(&C[(size_t)row * N + col], acc[mf][nf][r]);
            }
}

// ---------------- Merged QKV GEMM: phase Q (256x256) then phase KV (128x256) ----------
__global__ __launch_bounds__(512, 2) void gemm_qkv_all(const bf16* __restrict__ A,
                                                       const bf16* __restrict__ Bt,
                                                       bf16* __restrict__ q_r,
                                                       bf16* __restrict__ k_r,
                                                       bf16* __restrict__ vbuf,
                                                       const float2* __restrict__ tab,
                                                       int M, int K) {
    __shared__ __align__(16) char lds[131072];
    GEMM_COMMON_DEFS

    // ================= Phase Q: cols [0,4096), 256^2 tiles =================
    {
        const int nby = M >> 8;
        const int by = wg % nby, bx = wg / nby;
        const int brow = by << 8, bcol = bx << 8;
        const bf16* Ag = A + (size_t)brow * K;
        const bf16* Bg = Bt + (size_t)bcol * K;
        const int nt = K >> 6;
#define LDB(cbuf, nh, nf, ks) \
    (*(const bf16x8*)&lds[65536 + (cbuf)*32768 + (((wcol>>1)*128 + (wcol&1)*32 + (nh)*64 + (nf)*16 + lq))*128 + ((((ks)*4 + lg)) ^ (lq & 7))*16])
        GEMM_PROLOG_AND_LOOP(remap)
#undef LDB
        const int trow = brow + wrow * 128;
        const float sc = 0.12751741230963214f;   // log2e/sqrt(128)
#pragma unroll
        for (int mf = 0; mf < 8; ++mf)
#pragma unroll
            for (int j = 0; j < 2; ++j)
#pragma unroll
                for (int r = 0; r < 4; ++r) {
                    int row = trow + mf*16 + lg*4 + r;
                    int bb = row >> 11, tt = row & 2047;
                    int i  = (wcol&1)*32 + j*16 + lq;          // 0..63
                    float2 cs = tab[tt*64 + i];
                    float x0 = acc[mf][j][r], x1 = acc[mf][j+2][r];
                    float y0 = (x0*cs.x - x1*cs.y) * sc;
                    float y1 = (x1*cs.x + x0*cs.y) * sc;
                    int col0 = bcol + (wcol>>1)*128 + i;
                    int h = col0 >> 7, hd = col0 & 127;
                    bf16* dst = q_r + ((size_t)(bb*NH_ + h)*T_ + tt)*HD_;
                    dst[hd]      = __float2bfloat16(y0);
                    dst[hd + 64] = __float2bfloat16(y1);
                }
    }
    __builtin_amdgcn_s_barrier();   // all waves past Q phase (LDS reads done)

    // ================= Phase KV: cols [4096,6144), 128x256 tiles =================
    {
        const int nby = M >> 7;                    // 32
        const int by = wg % nby, bx = wg / nby;    // bx 0..7
        const int brow = by << 7;
        const int bcolr = bx << 8;                 // within KV region [0,2048)
        const bf16* Ag = A + (size_t)brow * K;
        const bf16* Bg = Bt + ((size_t)(NH_*HD_) + bcolr) * K;
        const int nt = K >> 6;

#define KV_STAGE_A(t2, cbuf, hf)                                                        \
    {                                                                                   \
        const char* src = (const char*)Ag +                                             \
            ((size_t)((hf) * 64 + srow) * K + (size_t)(t2) * 64) * 2 + schunk * 16;     \
        char* dst = &lds[(cbuf) * 16384 + ((hf) * 64 + (wid << 3)) * 128];              \
        __builtin_amdgcn_global_load_lds(                                               \
            (const __attribute__((address_space(1))) void*)src,                         \
            (__attribute__((address_space(3))) void*)dst, 16, 0, 0);                    \
    }
#define KV_STAGE_B(t2, cbuf, hf)                                                        \
    {                                                                                   \
        _Pragma("unroll")                                                               \
        for (int l = 0; l < 2; ++l) {                                                   \
            const int r0 = (hf) * 128 + l * 64;                                         \
            const char* src = (const char*)Bg +                                         \
                ((size_t)(r0 + srow) * K + (size_t)(t2) * 64) * 2 + schunk * 16;        \
            char* dst = &lds[32768 + (cbuf) * 32768 + (r0 + (wid << 3)) * 128];         \
            __builtin_amdgcn_global_load_lds(                                           \
                (const __attribute__((address_space(1))) void*)src,                     \
                (__attribute__((address_space(3))) void*)dst, 16, 0, 0);                \
        }                                                                               \
    }
#define KV_LDA(cbuf, mh, f, ks) \
    (*(const bf16x8*)&lds[(cbuf)*16384 + (wrow*64 + (mh)*32 + (f)*16 + lq)*128 + ((((ks)*4 + lg)) ^ (lq & 7))*16])
#define KV_LDB(cbuf, nh, nf, ks) \
    (*(const bf16x8*)&lds[32768 + (cbuf)*32768 + (((wcol>>1)*128 + (wcol&1)*32 + (nh)*64 + (nf)*16 + lq))*128 + ((((ks)*4 + lg)) ^ (lq & 7))*16])
#define KV_READ_A(cbuf, mh) \
    { _Pragma("unroll") for (int f = 0; f < 2; ++f) { a[f][0] = KV_LDA(cbuf, mh, f, 0); a[f][1] = KV_LDA(cbuf, mh, f, 1); } }
#define KV_READ_B(cbuf, nh, breg) \
    { _Pragma("unroll") for (int nf = 0; nf < 2; ++nf) { breg[nf][0] = KV_LDB(cbuf, nh, nf, 0); breg[nf][1] = KV_LDB(cbuf, nh, nf, 1); } }
#define KV_MFMA(am, an, breg)                                                    \
    { __builtin_amdgcn_s_setprio(1);                                             \
      _Pragma("unroll") for (int f = 0; f < 2; ++f)                              \
          _Pragma("unroll") for (int nf = 0; nf < 2; ++nf)                       \
              _Pragma("unroll") for (int ks = 0; ks < 2; ++ks)                   \
                  acc[(am) + f][(an) + nf] = mfma16(a[f][ks], breg[nf][ks],      \
                                                    acc[(am) + f][(an) + nf]);   \
      __builtin_amdgcn_s_setprio(0); }

        f32x4 acc[4][4] = {};
        bf16x8 a[2][2], b0[2][2], b1[2][2];

        KV_STAGE_A(0, 0, 0); KV_STAGE_A(0, 0, 1);
        KV_STAGE_B(0, 0, 0); KV_STAGE_B(0, 0, 1);
        KV_STAGE_B(1, 1, 0); KV_STAGE_B(1, 1, 1);
        asm volatile("s_waitcnt vmcnt(4)" ::: "memory");
        BAR();

        for (int it = 0; it < (nt >> 1); ++it) {
            const int u = 2 * it;
            const bool more = (u + 2) < nt;
            const bool more3 = (u + 3) < nt;

            KV_READ_A(0, 0); KV_READ_B(0, 0, b0);
            KV_STAGE_A(u + 1, 1, 0);
            KV_MFMA(0, 0, b0);
            BAR();
            KV_READ_B(0, 1, b1);
            KV_STAGE_A(u + 1, 1, 1);
            KV_MFMA(0, 2, b1);
            BAR();
            KV_READ_A(0, 1);
            if (more) KV_STAGE_B(u + 2, 0, 0);
            KV_MFMA(2, 2, b1);
            BAR();
            if (more) KV_STAGE_B(u + 2, 0, 1);
            KV_MFMA(2, 0, b0);
            if (more) asm volatile("s_waitcnt vmcnt(4)" ::: "memory");
            else      asm volatile("s_waitcnt vmcnt(0)" ::: "memory");
            BAR();
            KV_READ_A(1, 0); KV_READ_B(1, 0, b0);
            if (more) KV_STAGE_A(u + 2, 0, 0);
            KV_MFMA(0, 0, b0);
            BAR();
            KV_READ_B(1, 1, b1);
            if (more) KV_STAGE_A(u + 2, 0, 1);
            KV_MFMA(0, 2, b1);
            BAR();
            KV_READ_A(1, 1);
            if (more3) KV_STAGE_B(u + 3, 1, 0);
            KV_MFMA(2, 2, b1);
            BAR();
            if (more3) KV_STAGE_B(u + 3, 1, 1);
            KV_MFMA(2, 0, b0);
            if (more3) asm volatile("s_waitcnt vmcnt(4)" ::: "memory");
            else       asm volatile("s_waitcnt vmcnt(0)" ::: "memory");
            BAR();
        }

        const int trow = brow + wrow * 64;
        if (bcolr >= 1024) {
            // V: raw store into compact [row][1024] buffer (remapped cols)
#pragma unroll
            for (int mf = 0; mf < 4; ++mf)
#pragma unroll
                for (int j = 0; j < 4; ++j)
#pragma unroll
                    for (int r = 0; r < 4; ++r) {
                        int row = trow + (mf>>1)*32 + (mf&1)*16 + lg*4 + r;
                        int col = bcolr + (wcol>>1)*128 + (wcol&1)*32 + (j>>1)*64 + (j&1)*16 + lq - 1024;
                        vbuf[(size_t)row * (NKV_*HD_) + col] = __float2bfloat16(acc[mf][j][r]);
                    }
        } else {
            // K: RoPE, no scale
#pragma unroll
            for (int mf = 0; mf < 4; ++mf)
#pragma unroll
                for (int j = 0; j < 2; ++j)
#pragma unroll
                    for (int r = 0; r < 4; ++r) {
                        int row = trow + (mf>>1)*32 + (mf&1)*16 + lg*4 + r;
                        int bb = row >> 11, tt = row & 2047;
                        int i  = (wcol&1)*32 + j*16 + lq;
                        float2 cs = tab[tt*64 + i];
                        float x0 = acc[mf][j][r], x1 = acc[mf][j+2][r];
                        float y0 = x0*cs.x - x1*cs.y;
                        float y1 = x1*cs.x + x0*cs.y;
                        int col0 = bcolr + (wcol>>1)*128 + i;
                        int h = col0 >> 7, hd = col0 & 127;
                        bf16* dst = k_r + ((size_t)(bb*NKV_ + h)*T_ + tt)*HD_;
                        dst[hd]      = __float2bfloat16(y0);
                        dst[hd + 64] = __float2bfloat16(y1);
                    }
        }
#undef KV_STAGE_A
#undef KV_STAGE_B
#undef KV_LDA
#undef KV_LDB
#undef KV_READ_A
#undef KV_READ_B
#undef KV_MFMA
    }
}

#undef GEMM_PROLOG_AND_LOOP
#undef GEMM_COMMON_DEFS
#undef STAGE_HALF
#undef LDA
#undef READ_A
#undef READ_B
#undef MFMA_Q
#undef BAR

// ---------------- V transpose: vbuf [B*T][NKV*HD] -> vt [B,NKV,HD,T] ----------------
__global__ __launch_bounds__(256) void vtrans(const bf16* __restrict__ vbuf,
                                              bf16* __restrict__ vt) {
    __shared__ bf16 tile[32][33];
    int gx = blockIdx.x;               // [b(1)|kv(3)|tt(6)|dt(2)]
    int dt = gx & 3;
    int tt = (gx >> 2) & 63;
    int kv = (gx >> 8) & 7;
    int b  = gx >> 11;
    int d0 = dt * 32, t0 = tt * 32;
    int tx = threadIdx.x & 31, ty = threadIdx.x >> 5;

    const bf16* src = vbuf + (size_t)(b * T_ + t0) * (NKV_*HD_) + kv * HD_ + d0;
#pragma unroll
    for (int p = 0; p < 4; ++p)
        tile[p*8 + ty][tx] = src[(size_t)(p*8 + ty) * (NKV_*HD_) + tx];
    __syncthreads();
    bf16* dst = vt + ((size_t)((b * NKV_ + kv) * HD_ + d0)) * T_ + t0;
#pragma unroll
    for (int p = 0; p < 4; ++p)
        dst[(size_t)(p*8 + ty) * T_ + tx] = tile[tx][p*8 + ty];
}

// ---------------- Flash attention (causal, GQA): 16-wave, K+V LDS, reg-P ----------------
// 512 single-qt blocks; order: lin<256 -> qt=4+(lin>>6) (heavy), else qt=3-((lin-256)>>6).
// Round-robin dispatch pairs each CU with qt_h + qt_l summing to 9 units (uniform).
// LDS = 64 KB (Ks+Vs only) -> 2 blocks/CU = 8 waves/SIMD (double TLP vs R17).
// P redistribution to MFMA A-fragments is done IN-REGISTER via lane shuffles
// (replaces the 36.8 KB p_lds roundtrip): lane (lq,lg), ks needs
// P[q=lq][k=32ks+8lg+i] = quad n=2ks+(lg>=2) from lanes lg'=(lg&1)*2+{0,1}.
__global__ __launch_bounds__(1024) void fattn(const bf16* __restrict__ Q,
                                              const bf16* __restrict__ Kt,
                                              const bf16* __restrict__ VT,
                                              bf16* __restrict__ O) {
    const int lin = blockIdx.x;          // 512 blocks
    const int kv = lin & 7;
    const int b  = (lin >> 3) & 1;
    const int h  = kv * 4 + ((lin >> 4) & 3);   // GROUPS=4
    const int qg = lin >> 6;                    // 0..7
    const int qt = (qg < 4) ? (4 + qg) : (7 - qg);   // 4,5,6,7,3,2,1,0

    const int tid = threadIdx.x, wid = tid >> 6, lane = tid & 63;  // wid 0..15
    const int lq = lane & 15, lg = lane >> 4;

    const bf16* Kp = Kt + (size_t)(b * NKV_ + kv) * T_ * HD_;
    const bf16* Vp = VT + (size_t)(b * NKV_ + kv) * HD_ * T_;

    __shared__ __align__(16) bf16 Ks[2][64][128];     // 32 KB (chunk ^ row&15)
    __shared__ __align__(16) bf16 Vs[2][128][64];     // 32 KB (chunk ^ row&7)

    const float THR_L2 = 11.5416f;   // 8 * log2(e)

#define STAGE_KV(cbuf, tt)                                                           \
    { {                                                                              \
        int krow = wid * 4 + (lane >> 4);                                            \
        int kch  = (lane & 15) ^ (krow & 15);                                        \
        const bf16* ksrc = Kp + (size_t)((tt) * 64 + krow) * HD_ + kch * 8;          \
        __builtin_amdgcn_global_load_lds(                                            \
            (const __attribute__((address_space(1))) void*)ksrc,                     \
            (__attribute__((address_space(3))) void*)&Ks[cbuf][wid*4][0],            \
            16, 0, 0);                                                               \
      }                                                                              \
      {                                                                              \
        int vrow = wid * 8 + (lane >> 3);                                            \
        int vch  = (lane & 7) ^ (vrow & 7);                                          \
        const bf16* vsrc = Vp + (size_t)vrow * T_ + (tt) * 64 + vch * 8;             \
        __builtin_amdgcn_global_load_lds(                                            \
            (const __attribute__((address_space(1))) void*)vsrc,                     \
            (__attribute__((address_space(3))) void*)&Vs[cbuf][wid*8][0],            \
            16, 0, 0);                                                               \
      } }

    const int q0 = qt * 256 + wid * 16;   // this wave's 16 q rows
    const int kv_end = q0 + 16;           // per-wave causal bound
    const int NT = (qt + 1) * 4;          // KV tiles for this block

    const bf16* Qp = Q + ((size_t)(b * NH_ + h) * T_ + q0) * HD_;
    bf16x8 qf[4];
#pragma unroll
    for (int c = 0; c < 4; ++c)
        qf[c] = *(const bf16x8*)&Qp[(size_t)lq * HD_ + c * 32 + lg * 8];

    f32x4 oacc[8] = {};
    float m_r = -INFINITY;
    float l_r = 0.f;

    STAGE_KV(0, 0);
    STAGE_KV(1, 1);
    asm volatile("s_waitcnt vmcnt(2)" ::: "memory");   // tile 0 landed
    __builtin_amdgcn_s_barrier();

    for (int t = 0; t < NT; ++t) {
        const int cb = t & 1;
        const int t0 = t * 64;

        if (t0 < kv_end) {   // wave-uniform predicate; barriers stay outside
            // ---- S^T = K @ Q^T (K from LDS, swizzled read) ----
            f32x4 st[4] = {};
#pragma unroll
            for (int n = 0; n < 4; ++n) {
                bf16x8 kf[4];
#pragma unroll
                for (int c = 0; c < 4; ++c)
                    kf[c] = *(const bf16x8*)((const char*)&Ks[cb][n*16 + lq][0]
                                              + (((c*4 + lg) ^ lq) << 4));
                __builtin_amdgcn_s_setprio(1);
#pragma unroll
                for (int c = 0; c < 4; ++c)
                    st[n] = mfma16(kf[c], qf[c], st[n]);
                __builtin_amdgcn_s_setprio(0);
            }

            // ---- causal mask (swapped layout) ----
            const int qq = q0 + lq;
#pragma unroll
            for (int n = 0; n < 4; ++n)
#pragma unroll
                for (int r = 0; r < 4; ++r) {
                    int kk = t0 + n*16 + lg*4 + r;
                    if (kk > qq) st[n][r] = -INFINITY;
                }

            // ---- row max (15 in-reg + 2 shfl) ----
            float rmax = st[0][0];
#pragma unroll
            for (int n = 0; n < 4; ++n)
#pragma unroll
                for (int r = 0; r < 4; ++r) rmax = fmaxf(rmax, st[n][r]);
            rmax = fmaxf(rmax, __shfl_xor(rmax, 16));
            rmax = fmaxf(rmax, __shfl_xor(rmax, 32));

            // ---- defer-max (THR = 8 nats, log2 domain) ----
            if (__any(rmax - m_r > THR_L2)) {
                float mnew = fmaxf(m_r, rmax);
                float alpha = exp2f(m_r - mnew);   // first tile: exp2(-inf)=0
                m_r = mnew;
                l_r *= alpha;
#pragma unroll
                for (int r = 0; r < 4; ++r) {
                    float a_pv = __shfl(alpha, lg*4 + r);   // to PV layout
#pragma unroll
                    for (int f = 0; f < 8; ++f) oacc[f][r] *= a_pv;
                }
            }

            // ---- exp2 + row sum ----
            float rsum = 0.f;
#pragma unroll
            for (int n = 0; n < 4; ++n)
#pragma unroll
                for (int r = 0; r < 4; ++r) {
                    float p = exp2f(st[n][r] - m_r);
                    st[n][r] = p;
                    rsum += p;
                }
            rsum += __shfl_xor(rsum, 16);
            rsum += __shfl_xor(rsum, 32);
            l_r += rsum;

            // ---- pack P quads to bf16 (pk[n] = P[q=lq][k=n*16+lg*4 .. +3]) ----
            uint2 pk[4];
#pragma unroll
            for (int n = 0; n < 4; ++n) {
                union { bf16 hh[4]; uint2 u; } w;
#pragma unroll
                for (int r = 0; r < 4; ++r) w.hh[r] = __float2bfloat16(st[n][r]);
                pk[n] = w.u;
            }

            // ---- in-register redistribution to A-fragment layout ----
            const int src0 = ((lg & 1) << 5) + lq;   // lane of lg' = (lg&1)*2
            const int src1 = src0 + 16;              // lg' + 1
            bf16x8 pa[2];
#pragma unroll
            for (int ks = 0; ks < 2; ++ks) {
                int a0x = __shfl((int)pk[2*ks].x,   src0);
                int a0y = __shfl((int)pk[2*ks].y,   src0);
                int a1x = __shfl((int)pk[2*ks].x,   src1);
                int a1y = __shfl((int)pk[2*ks].y,   src1);
                int b0x = __shfl((int)pk[2*ks+1].x, src0);
                int b0y = __shfl((int)pk[2*ks+1].y, src0);
                int b1x = __shfl((int)pk[2*ks+1].x, src1);
                int b1y = __shfl((int)pk[2*ks+1].y, src1);
                union { int u[4]; bf16x8 v; } w;
                bool hiHalf = (lg >= 2);             // n = 2ks+1 for lg 2,3
                w.u[0] = hiHalf ? b0x : a0x;
                w.u[1] = hiHalf ? b0y : a0y;
                w.u[2] = hiHalf ? b1x : a1x;
                w.u[3] = hiHalf ? b1y : a1y;
                pa[ks] = w.v;
            }

            // ---- O += P @ V (V from LDS, swizzled read; ks=0 then ks=1) ----
#pragma unroll
            for (int ks = 0; ks < 2; ++ks) {
                bf16x8 vf[8];
#pragma unroll
                for (int f = 0; f < 8; ++f)
                    vf[f] = *(const bf16x8*)((const char*)&Vs[cb][f*16 + lq][0]
                                              + (((ks*4 + lg) ^ (lq & 7)) << 4));
                __builtin_amdgcn_s_setprio(1);
#pragma unroll
                for (int f = 0; f < 8; ++f)
                    oacc[f] = mfma16(pa[ks], vf[f], oacc[f]);
                __builtin_amdgcn_s_setprio(0);
            }
        }

        // ---- pipeline maintenance (uniform; raw barriers + counted vmcnt) ----
        __builtin_amdgcn_s_barrier();          // all waves done reading buf[cb]
        if (t + 2 < NT) {
            STAGE_KV(cb, t + 2);               // refill freed buffer (2 loads)
            asm volatile("s_waitcnt vmcnt(2)" ::: "memory");   // own t+1 landed
        } else {
            asm volatile("s_waitcnt vmcnt(0)" ::: "memory");
        }
        __builtin_amdgcn_s_barrier();          // tile t+1 visible to all
    }

    // ---- epilogue: 1/l broadcast to PV layout, store [B,T,NH,HD] ----
    {
        float rinv = __builtin_amdgcn_rcpf(l_r);
#pragma unroll
        for (int r = 0; r < 4; ++r) {
            float rl = __shfl(rinv, lg*4 + r);
            int row = q0 + lg*4 + r;
#pragma unroll
            for (int f = 0; f < 8; ++f) {
                int d = f*16 + lq;
                O[((size_t)(b * T_ + row) * NH_ + h) * HD_ + d] =
                    __float2bfloat16(oacc[f][r] * rl);
            }
        }
    }
#undef STAGE_KV
}

// ---------------- launch ----------------
extern "C" void kernel_launch(void* const* d_in, const int* in_sizes, int n_in,
                              void* d_out, int out_size, void* d_ws, size_t ws_size,
                              hipStream_t stream) {
    const float* x  = (const float*)d_in[0];
    const float* wq = (const float*)d_in[1];
    const float* wk = (const float*)d_in[2];
    const float* wv = (const float*)d_in[3];
    const float* wo = (const float*)d_in[4];
    float* out = (float*)d_out;

    bf16* ws    = (bf16*)d_ws;
    bf16* xb    = ws;
    bf16* wqkvT = xb + (size_t)M_ * C_;
    bf16* qr_wo = wqkvT + (size_t)QKVN_ * C_;
    bf16* region = qr_wo + (size_t)C_ * C_;
    bf16* k_r  = region;
    bf16* vt   = k_r + (size_t)B_ * NKV_ * T_ * HD_;
    bf16* vbuf = vt  + (size_t)B_ * NKV_ * T_ * HD_;
    float2* tab = (float2*)(vbuf + (size_t)B_ * T_ * NKV_ * HD_);

    bf16* attn = xb;      // fattn output (xb dead as A after the gemms)

    // 1) cast x; fused wq|wk|wv transpose; rope table
    cast_f32_bf16<<<(M_ * C_ / 4 + 255) / 256, 256, 0, stream>>>(x, xb, M_ * C_ / 4);
    transpose_cast3<<<dim3(192, 128), 256, 0, stream>>>(wq, wk, wv, wqkvT, C_);
    rope_tab<<<(T_ * 64) / 256, 256, 0, stream>>>(tab);

    // 2) merged QKV GEMM (256 blocks: 1.0x Q-tile + 0.5x KV-tile each)
    gemm_qkv_all<<<dim3(256), 512, 0, stream>>>(
        xb, wqkvT, qr_wo, k_r, vbuf, tab, M_, C_);

    // 3) V transpose
    vtrans<<<B_ * NKV_ * (T_ / 32) * (HD_ / 32), 256, 0, stream>>>(vbuf, vt);

    // 4) attention (512 single-qt blocks x 1024 threads, 2 blocks/CU)
    fattn<<<dim3(512), 1024, 0, stream>>>(qr_wo, k_r, vt, attn);

    // 5) wo transpose into freed q_r region, then output projection
    transpose_cast<<<dim3(128, 128), 256, 0, stream>>>(wo, qr_wo, NH_ * HD_, C_);
    gemm256<float><<<dim3((C_ / 256) * (M_ / 256)), 512, 0, stream>>>(attn, qr_wo, out, M_, C_, C_);
}

// Round 19
// 465.533 us; speedup vs baseline: 1.0199x; 1.0199x over previous
//
#include <hip/hip_runtime.h>
#include <hip/hip_bf16.h>
#include <math.h>

#define B_ 2
#define T_ 2048
#define C_ 4096
#define NH_ 32
#define NKV_ 8
#define HD_ 128
#define M_ (B_*T_)              // 4096 rows
#define QKVN_ (NH_*HD_ + 2*NKV_*HD_)  // 6144

using bf16 = __hip_bfloat16;
typedef __bf16 bf16x8 __attribute__((ext_vector_type(8)));
typedef float f32x4 __attribute__((ext_vector_type(4)));

__device__ inline f32x4 mfma16(bf16x8 a, bf16x8 b, f32x4 c) {
    return __builtin_amdgcn_mfma_f32_16x16x32_bf16(a, b, c, 0, 0, 0);
}

// ---------------- merged prep: cast x | transpose wq,wk,wv | rope table ----------------
// blocks [0,16384): cast x (f32->bf16, x4)
// blocks [16384, 16384+24576): transpose_cast3 tile (nt = r%192, k0 = (r/192)<<5)
// blocks [40960, 41472): rope table
__global__ __launch_bounds__(256) void prep_all(const float* __restrict__ x,
                                                const float* __restrict__ wq,
                                                const float* __restrict__ wk,
                                                const float* __restrict__ wv,
                                                bf16* __restrict__ xb,
                                                bf16* __restrict__ wqkvT,
                                                float2* __restrict__ tab) {
    int bid = blockIdx.x;
    if (bid < 16384) {
        int i = bid * 256 + threadIdx.x;
        float4 v = reinterpret_cast<const float4*>(x)[i];
        union { bf16 h[4]; uint2 u; } o;
        o.h[0] = __float2bfloat16(v.x);
        o.h[1] = __float2bfloat16(v.y);
        o.h[2] = __float2bfloat16(v.z);
        o.h[3] = __float2bfloat16(v.w);
        reinterpret_cast<uint2*>(xb)[i] = o.u;
    } else if (bid < 16384 + 24576) {
        __shared__ float tile[32][33];
        int r = bid - 16384;
        int nt = r % 192, k0 = (r / 192) << 5;
        int tx = threadIdx.x & 31, ty = threadIdx.x >> 5;
        const float* src; int N, nloc;
        if (nt < 128)      { src = wq; N = 4096; nloc = nt << 5; }
        else if (nt < 160) { src = wk; N = 1024; nloc = (nt - 128) << 5; }
        else               { src = wv; N = 1024; nloc = (nt - 160) << 5; }
#pragma unroll
        for (int p = 0; p < 4; ++p)
            tile[p*8 + ty][tx] = src[(size_t)(k0 + p*8 + ty) * N + nloc + tx];
        __syncthreads();
        int nglob = nt << 5;
#pragma unroll
        for (int p = 0; p < 4; ++p)
            wqkvT[(size_t)(nglob + p*8 + ty) * C_ + k0 + tx] = __float2bfloat16(tile[tx][p*8 + ty]);
    } else {
        int idx = (bid - 16384 - 24576) * 256 + threadIdx.x;   // t*64 + i
        int i = idx & 63, t = idx >> 6;
        float inv = exp2f((float)i * -0.20762050593045952f);
        float th = (float)t * inv;
        tab[idx] = make_float2(cosf(th), sinf(th));
    }
}

// ---------------- transpose + cast: in f32 [K][N] -> out bf16 [N][K] ----------------
__global__ __launch_bounds__(256) void transpose_cast(const float* __restrict__ in,
                                                      bf16* __restrict__ out, int K, int N) {
    __shared__ float tile[32][33];
    int tx = threadIdx.x & 31, ty = threadIdx.x >> 5;  // 32 x 8
    int n0 = blockIdx.x << 5, k0 = blockIdx.y << 5;
#pragma unroll
    for (int p = 0; p < 4; ++p)
        tile[p*8 + ty][tx] = in[(size_t)(k0 + p*8 + ty) * N + n0 + tx];
    __syncthreads();
#pragma unroll
    for (int p = 0; p < 4; ++p)
        out[(size_t)(n0 + p*8 + ty) * K + k0 + tx] = __float2bfloat16(tile[tx][p*8 + ty]);
}

// ======== shared GEMM phase machinery (256x256, BK=64, 8 waves, 8-phase) ========
// R14-proven schedule (register ceiling: do not add operand registers).
#define GEMM_PROLOG_AND_LOOP(TAG)                                                       \
    f32x4 acc[8][4] = {};                                                               \
    bf16x8 a[4][2], b0[2][2], b1[2][2];                                                 \
    STAGE_HALF(Ag, 0,     0, 0, 0); STAGE_HALF(Ag, 0,     0, 0, 1);                     \
    STAGE_HALF(Bg, 65536, 0, 0, 0); STAGE_HALF(Bg, 65536, 0, 0, 1);                     \
    STAGE_HALF(Bg, 65536, 1, 1, 0); STAGE_HALF(Bg, 65536, 1, 1, 1);                     \
    asm volatile("s_waitcnt vmcnt(4)" ::: "memory");                                    \
    BAR();                                                                              \
    for (int it = 0; it < (nt >> 1); ++it) {                                            \
        const int u = 2 * it;                                                           \
        const bool more = (u + 2) < nt;                                                 \
        const bool more3 = (u + 3) < nt;                                                \
        READ_A(0, 0); READ_B(0, 0, b0);                                                 \
        STAGE_HALF(Ag, 0, u + 1, 1, 0);                                                 \
        MFMA_Q(0, 0, b0);                                                               \
        BAR();                                                                          \
        READ_B(0, 1, b1);                                                               \
        STAGE_HALF(Ag, 0, u + 1, 1, 1);                                                 \
        MFMA_Q(0, 2, b1);                                                               \
        BAR();                                                                          \
        READ_A(0, 1);                                                                   \
        if (more) STAGE_HALF(Bg, 65536, u + 2, 0, 0);                                   \
        MFMA_Q(4, 2, b1);                                                               \
        BAR();                                                                          \
        if (more) STAGE_HALF(Bg, 65536, u + 2, 0, 1);                                   \
        MFMA_Q(4, 0, b0);                                                               \
        if (more) asm volatile("s_waitcnt vmcnt(8)" ::: "memory");                      \
        else      asm volatile("s_waitcnt vmcnt(4)" ::: "memory");                      \
        BAR();                                                                          \
        READ_A(1, 0); READ_B(1, 0, b0);                                                 \
        if (more) STAGE_HALF(Ag, 0, u + 2, 0, 0);                                       \
        MFMA_Q(0, 0, b0);                                                               \
        BAR();                                                                          \
        READ_B(1, 1, b1);                                                               \
        if (more) STAGE_HALF(Ag, 0, u + 2, 0, 1);                                       \
        MFMA_Q(0, 2, b1);                                                               \
        if (more) asm volatile("s_waitcnt vmcnt(8)" ::: "memory");                      \
        else      asm volatile("s_waitcnt vmcnt(0)" ::: "memory");                      \
        BAR();                                                                          \
        READ_A(1, 1);                                                                   \
        if (more3) STAGE_HALF(Bg, 65536, u + 3, 1, 0);                                  \
        MFMA_Q(4, 2, b1);                                                               \
        BAR();                                                                          \
        if (more3) STAGE_HALF(Bg, 65536, u + 3, 1, 1);                                  \
        MFMA_Q(4, 0, b0);                                                               \
        if (more3) asm volatile("s_waitcnt vmcnt(4)" ::: "memory");                     \
        else       asm volatile("s_waitcnt vmcnt(0)" ::: "memory");                     \
        BAR();                                                                          \
    }

#define GEMM_COMMON_DEFS                                                                \
    const int tid = threadIdx.x;                                                        \
    const int wid = tid >> 6, lane = tid & 63;                                          \
    const int lq = lane & 15, lg = lane >> 4;                                           \
    const int wrow = wid >> 2, wcol = wid & 3;                                          \
    const int nwg = gridDim.x;                                                          \
    const int q8 = nwg >> 3;                                                            \
    const int wg = (blockIdx.x & 7) * q8 + (blockIdx.x >> 3);                           \
    const int srow = (wid << 3) + (lane >> 3);                                          \
    const int schunk = (lane & 7) ^ ((lane >> 3) & 7);

#define STAGE_HALF(gbase, ldsoff, t2, cbuf, hf)                                         \
    {                                                                                   \
        _Pragma("unroll")                                                               \
        for (int l = 0; l < 2; ++l) {                                                   \
            const int r0 = (hf) * 128 + l * 64;                                         \
            const char* src = (const char*)(gbase) +                                    \
                ((size_t)(r0 + srow) * K + (size_t)(t2) * 64) * 2 + schunk * 16;        \
            char* dst = &lds[(ldsoff) + (cbuf) * 32768 + (r0 + (wid << 3)) * 128];      \
            __builtin_amdgcn_global_load_lds(                                           \
                (const __attribute__((address_space(1))) void*)src,                     \
                (__attribute__((address_space(3))) void*)dst, 16, 0, 0);                \
        }                                                                               \
    }

#define LDA(cbuf, mh, mf, ks) \
    (*(const bf16x8*)&lds[(cbuf)*32768 + (wrow*128 + (mh)*64 + (mf)*16 + lq)*128 + ((((ks)*4 + lg)) ^ (lq & 7))*16])

#define READ_A(cbuf, mh) \
    { _Pragma("unroll") for (int mf = 0; mf < 4; ++mf) { a[mf][0] = LDA(cbuf, mh, mf, 0); a[mf][1] = LDA(cbuf, mh, mf, 1); } }
#define READ_B(cbuf, nh, breg) \
    { _Pragma("unroll") for (int nf = 0; nf < 2; ++nf) { breg[nf][0] = LDB(cbuf, nh, nf, 0); breg[nf][1] = LDB(cbuf, nh, nf, 1); } }
#define MFMA_Q(am, an, breg)                                                     \
    { __builtin_amdgcn_s_setprio(1);                                             \
      _Pragma("unroll") for (int mf = 0; mf < 4; ++mf)                           \
          _Pragma("unroll") for (int nf = 0; nf < 2; ++nf)                       \
              _Pragma("unroll") for (int ks = 0; ks < 2; ++ks)                   \
                  acc[(am) + mf][(an) + nf] = mfma16(a[mf][ks], breg[nf][ks],    \
                                                     acc[(am) + mf][(an) + nf]); \
      __builtin_amdgcn_s_setprio(0); }
#define BAR() __builtin_amdgcn_s_barrier()

// ---------------- plain 256x256 GEMM (out-proj): C[M][N] = A @ Bt^T ----------------
__device__ inline void store_out(float* p, float v) { *p = v; }
__device__ inline void store_out(bf16*  p, float v) { *p = __float2bfloat16(v); }

template <typename OutT>
__global__ __launch_bounds__(512, 2) void gemm256(const bf16* __restrict__ A,
                                                  const bf16* __restrict__ Bt,
                                                  OutT* __restrict__ C,
                                                  int M, int N, int K) {
    __shared__ __align__(16) char lds[131072];
    GEMM_COMMON_DEFS
    const int nby = M >> 8;
    const int by = wg % nby, bx = wg / nby;
    const int brow = by << 8, bcol = bx << 8;
    const bf16* Ag = A + (size_t)brow * K;
    const bf16* Bg = Bt + (size_t)bcol * K;
    const int nt = K >> 6;
#define LDB(cbuf, nh, nf, ks) \
    (*(const bf16x8*)&lds[65536 + (cbuf)*32768 + (wcol*64 + (nh)*32 + (nf)*16 + lq)*128 + ((((ks)*4 + lg)) ^ (lq & 7))*16])
    GEMM_PROLOG_AND_LOOP(plain)
#undef LDB
#pragma unroll
    for (int mf = 0; mf < 8; ++mf)
#pragma unroll
        for (int nf = 0; nf < 4; ++nf)
#pragma unroll
            for (int r = 0; r < 4; ++r) {
                int row = brow + wrow * 128 + mf * 16 + lg * 4 + r;
                int col = bcol + wcol * 64 + nf * 16 + lq;
                store_out(&C[(size_t)row * N + col], acc[mf][nf][r]);
            }
}

// ---------------- Merged QKV GEMM: phase Q (256x256) then phase KV (128x256) ----------
__global__ __launch_bounds__(512, 2) void gemm_qkv_all(const bf16* __restrict__ A,
                                                       const bf16* __restrict__ Bt,
                                                       bf16* __restrict__ q_r,
                                                       bf16* __restrict__ k_r,
                                                       bf16* __restrict__ vbuf,
                                                       const float2* __restrict__ tab,
                                                       int M, int K) {
    __shared__ __align__(16) char lds[131072];
    GEMM_COMMON_DEFS

    // ================= Phase Q: cols [0,4096), 256^2 tiles =================
    {
        const int nby = M >> 8;
        const int by = wg % nby, bx = wg / nby;
        const int brow = by << 8, bcol = bx << 8;
        const bf16* Ag = A + (size_t)brow * K;
        const bf16* Bg = Bt + (size_t)bcol * K;
        const int nt = K >> 6;
#define LDB(cbuf, nh, nf, ks) \
    (*(const bf16x8*)&lds[65536 + (cbuf)*32768 + (((wcol>>1)*128 + (wcol&1)*32 + (nh)*64 + (nf)*16 + lq))*128 + ((((ks)*4 + lg)) ^ (lq & 7))*16])
        GEMM_PROLOG_AND_LOOP(remap)
#undef LDB
        const int trow = brow + wrow * 128;
        const float sc = 0.12751741230963214f;   // log2e/sqrt(128)
#pragma unroll
        for (int mf = 0; mf < 8; ++mf)
#pragma unroll
            for (int j = 0; j < 2; ++j)
#pragma unroll
                for (int r = 0; r < 4; ++r) {
                    int row = trow + mf*16 + lg*4 + r;
                    int bb = row >> 11, tt = row & 2047;
                    int i  = (wcol&1)*32 + j*16 + lq;          // 0..63
                    float2 cs = tab[tt*64 + i];
                    float x0 = acc[mf][j][r], x1 = acc[mf][j+2][r];
                    float y0 = (x0*cs.x - x1*cs.y) * sc;
                    float y1 = (x1*cs.x + x0*cs.y) * sc;
                    int col0 = bcol + (wcol>>1)*128 + i;
                    int h = col0 >> 7, hd = col0 & 127;
                    bf16* dst = q_r + ((size_t)(bb*NH_ + h)*T_ + tt)*HD_;
                    dst[hd]      = __float2bfloat16(y0);
                    dst[hd + 64] = __float2bfloat16(y1);
                }
    }
    __builtin_amdgcn_s_barrier();   // all waves past Q phase (LDS reads done)

    // ================= Phase KV: cols [4096,6144), 128x256 tiles =================
    {
        const int nby = M >> 7;                    // 32
        const int by = wg % nby, bx = wg / nby;    // bx 0..7
        const int brow = by << 7;
        const int bcolr = bx << 8;                 // within KV region [0,2048)
        const bf16* Ag = A + (size_t)brow * K;
        const bf16* Bg = Bt + ((size_t)(NH_*HD_) + bcolr) * K;
        const int nt = K >> 6;

#define KV_STAGE_A(t2, cbuf, hf)                                                        \
    {                                                                                   \
        const char* src = (const char*)Ag +                                             \
            ((size_t)((hf) * 64 + srow) * K + (size_t)(t2) * 64) * 2 + schunk * 16;     \
        char* dst = &lds[(cbuf) * 16384 + ((hf) * 64 + (wid << 3)) * 128];              \
        __builtin_amdgcn_global_load_lds(                                               \
            (const __attribute__((address_space(1))) void*)src,                         \
            (__attribute__((address_space(3))) void*)dst, 16, 0, 0);                    \
    }
#define KV_STAGE_B(t2, cbuf, hf)                                                        \
    {                                                                                   \
        _Pragma("unroll")                                                               \
        for (int l = 0; l < 2; ++l) {                                                   \
            const int r0 = (hf) * 128 + l * 64;                                         \
            const char* src = (const char*)Bg +                                         \
                ((size_t)(r0 + srow) * K + (size_t)(t2) * 64) * 2 + schunk * 16;        \
            char* dst = &lds[32768 + (cbuf) * 32768 + (r0 + (wid << 3)) * 128];         \
            __builtin_amdgcn_global_load_lds(                                           \
                (const __attribute__((address_space(1))) void*)src,                     \
                (__attribute__((address_space(3))) void*)dst, 16, 0, 0);                \
        }                                                                               \
    }
#define KV_LDA(cbuf, mh, f, ks) \
    (*(const bf16x8*)&lds[(cbuf)*16384 + (wrow*64 + (mh)*32 + (f)*16 + lq)*128 + ((((ks)*4 + lg)) ^ (lq & 7))*16])
#define KV_LDB(cbuf, nh, nf, ks) \
    (*(const bf16x8*)&lds[32768 + (cbuf)*32768 + (((wcol>>1)*128 + (wcol&1)*32 + (nh)*64 + (nf)*16 + lq))*128 + ((((ks)*4 + lg)) ^ (lq & 7))*16])
#define KV_READ_A(cbuf, mh) \
    { _Pragma("unroll") for (int f = 0; f < 2; ++f) { a[f][0] = KV_LDA(cbuf, mh, f, 0); a[f][1] = KV_LDA(cbuf, mh, f, 1); } }
#define KV_READ_B(cbuf, nh, breg) \
    { _Pragma("unroll") for (int nf = 0; nf < 2; ++nf) { breg[nf][0] = KV_LDB(cbuf, nh, nf, 0); breg[nf][1] = KV_LDB(cbuf, nh, nf, 1); } }
#define KV_MFMA(am, an, breg)                                                    \
    { __builtin_amdgcn_s_setprio(1);                                             \
      _Pragma("unroll") for (int f = 0; f < 2; ++f)                              \
          _Pragma("unroll") for (int nf = 0; nf < 2; ++nf)                       \
              _Pragma("unroll") for (int ks = 0; ks < 2; ++ks)                   \
                  acc[(am) + f][(an) + nf] = mfma16(a[f][ks], breg[nf][ks],      \
                                                    acc[(am) + f][(an) + nf]);   \
      __builtin_amdgcn_s_setprio(0); }

        f32x4 acc[4][4] = {};
        bf16x8 a[2][2], b0[2][2], b1[2][2];

        KV_STAGE_A(0, 0, 0); KV_STAGE_A(0, 0, 1);
        KV_STAGE_B(0, 0, 0); KV_STAGE_B(0, 0, 1);
        KV_STAGE_B(1, 1, 0); KV_STAGE_B(1, 1, 1);
        asm volatile("s_waitcnt vmcnt(4)" ::: "memory");
        BAR();

        for (int it = 0; it < (nt >> 1); ++it) {
            const int u = 2 * it;
            const bool more = (u + 2) < nt;
            const bool more3 = (u + 3) < nt;

            KV_READ_A(0, 0); KV_READ_B(0, 0, b0);
            KV_STAGE_A(u + 1, 1, 0);
            KV_MFMA(0, 0, b0);
            BAR();
            KV_READ_B(0, 1, b1);
            KV_STAGE_A(u + 1, 1, 1);
            KV_MFMA(0, 2, b1);
            BAR();
            KV_READ_A(0, 1);
            if (more) KV_STAGE_B(u + 2, 0, 0);
            KV_MFMA(2, 2, b1);
            BAR();
            if (more) KV_STAGE_B(u + 2, 0, 1);
            KV_MFMA(2, 0, b0);
            if (more) asm volatile("s_waitcnt vmcnt(4)" ::: "memory");
            else      asm volatile("s_waitcnt vmcnt(0)" ::: "memory");
            BAR();
            KV_READ_A(1, 0); KV_READ_B(1, 0, b0);
            if (more) KV_STAGE_A(u + 2, 0, 0);
            KV_MFMA(0, 0, b0);
            BAR();
            KV_READ_B(1, 1, b1);
            if (more) KV_STAGE_A(u + 2, 0, 1);
            KV_MFMA(0, 2, b1);
            BAR();
            KV_READ_A(1, 1);
            if (more3) KV_STAGE_B(u + 3, 1, 0);
            KV_MFMA(2, 2, b1);
            BAR();
            if (more3) KV_STAGE_B(u + 3, 1, 1);
            KV_MFMA(2, 0, b0);
            if (more3) asm volatile("s_waitcnt vmcnt(4)" ::: "memory");
            else       asm volatile("s_waitcnt vmcnt(0)" ::: "memory");
            BAR();
        }

        const int trow = brow + wrow * 64;
        if (bcolr >= 1024) {
            // V: raw store into compact [row][1024] buffer (remapped cols)
#pragma unroll
            for (int mf = 0; mf < 4; ++mf)
#pragma unroll
                for (int j = 0; j < 4; ++j)
#pragma unroll
                    for (int r = 0; r < 4; ++r) {
                        int row = trow + (mf>>1)*32 + (mf&1)*16 + lg*4 + r;
                        int col = bcolr + (wcol>>1)*128 + (wcol&1)*32 + (j>>1)*64 + (j&1)*16 + lq - 1024;
                        vbuf[(size_t)row * (NKV_*HD_) + col] = __float2bfloat16(acc[mf][j][r]);
                    }
        } else {
            // K: RoPE, no scale
#pragma unroll
            for (int mf = 0; mf < 4; ++mf)
#pragma unroll
                for (int j = 0; j < 2; ++j)
#pragma unroll
                    for (int r = 0; r < 4; ++r) {
                        int row = trow + (mf>>1)*32 + (mf&1)*16 + lg*4 + r;
                        int bb = row >> 11, tt = row & 2047;
                        int i  = (wcol&1)*32 + j*16 + lq;
                        float2 cs = tab[tt*64 + i];
                        float x0 = acc[mf][j][r], x1 = acc[mf][j+2][r];
                        float y0 = x0*cs.x - x1*cs.y;
                        float y1 = x1*cs.x + x0*cs.y;
                        int col0 = bcolr + (wcol>>1)*128 + i;
                        int h = col0 >> 7, hd = col0 & 127;
                        bf16* dst = k_r + ((size_t)(bb*NKV_ + h)*T_ + tt)*HD_;
                        dst[hd]      = __float2bfloat16(y0);
                        dst[hd + 64] = __float2bfloat16(y1);
                    }
        }
#undef KV_STAGE_A
#undef KV_STAGE_B
#undef KV_LDA
#undef KV_LDB
#undef KV_READ_A
#undef KV_READ_B
#undef KV_MFMA
    }
}

#undef GEMM_PROLOG_AND_LOOP
#undef GEMM_COMMON_DEFS
#undef STAGE_HALF
#undef LDA
#undef READ_A
#undef READ_B
#undef MFMA_Q
#undef BAR

// ---------------- V transpose: vbuf [B*T][NKV*HD] -> vt [B,NKV,HD,T] ----------------
__global__ __launch_bounds__(256) void vtrans(const bf16* __restrict__ vbuf,
                                              bf16* __restrict__ vt) {
    __shared__ bf16 tile[32][33];
    int gx = blockIdx.x;               // [b(1)|kv(3)|tt(6)|dt(2)]
    int dt = gx & 3;
    int tt = (gx >> 2) & 63;
    int kv = (gx >> 8) & 7;
    int b  = gx >> 11;
    int d0 = dt * 32, t0 = tt * 32;
    int tx = threadIdx.x & 31, ty = threadIdx.x >> 5;

    const bf16* src = vbuf + (size_t)(b * T_ + t0) * (NKV_*HD_) + kv * HD_ + d0;
#pragma unroll
    for (int p = 0; p < 4; ++p)
        tile[p*8 + ty][tx] = src[(size_t)(p*8 + ty) * (NKV_*HD_) + tx];
    __syncthreads();
    bf16* dst = vt + ((size_t)((b * NKV_ + kv) * HD_ + d0)) * T_ + t0;
#pragma unroll
    for (int p = 0; p < 4; ++p)
        dst[(size_t)(p*8 + ty) * T_ + tx] = tile[tx][p*8 + ty];
}

// ---------------- Flash attention (causal, GQA): 16-wave, K+V LDS-staged (R17) ----------
__global__ __launch_bounds__(1024) void fattn(const bf16* __restrict__ Q,
                                              const bf16* __restrict__ Kt,
                                              const bf16* __restrict__ VT,
                                              bf16* __restrict__ O) {
    const int lin = blockIdx.x;          // 256 blocks
    const int kv = lin & 7;
    const int b  = (lin >> 3) & 1;
    const int idx = lin >> 4;            // 0..15
    const int h  = kv * 4 + (idx & 3);   // GROUPS=4
    const int jp = idx >> 2;             // 0..3 pair index (q-tiles jp, 7-jp)

    const int tid = threadIdx.x, wid = tid >> 6, lane = tid & 63;  // wid 0..15
    const int lq = lane & 15, lg = lane >> 4;

    const bf16* Kp = Kt + (size_t)(b * NKV_ + kv) * T_ * HD_;
    const bf16* Vp = VT + (size_t)(b * NKV_ + kv) * HD_ * T_;

    __shared__ __align__(16) bf16 Ks[2][64][128];     // 32 KB (chunk ^ row&15)
    __shared__ __align__(16) bf16 Vs[2][128][64];     // 32 KB (chunk ^ row&7)
    __shared__ __align__(16) bf16 p_lds[16][16][72];  // 36 KB per-wave P tiles

    const float THR_L2 = 11.5416f;   // 8 * log2(e)

#define STAGE_KV(cbuf, tt)                                                           \
    { {                                                                              \
        int krow = wid * 4 + (lane >> 4);                                            \
        int kch  = (lane & 15) ^ (krow & 15);                                        \
        const bf16* ksrc = Kp + (size_t)((tt) * 64 + krow) * HD_ + kch * 8;          \
        __builtin_amdgcn_global_load_lds(                                            \
            (const __attribute__((address_space(1))) void*)ksrc,                     \
            (__attribute__((address_space(3))) void*)&Ks[cbuf][wid*4][0],            \
            16, 0, 0);                                                               \
      }                                                                              \
      {                                                                              \
        int vrow = wid * 8 + (lane >> 3);                                            \
        int vch  = (lane & 7) ^ (vrow & 7);                                          \
        const bf16* vsrc = Vp + (size_t)vrow * T_ + (tt) * 64 + vch * 8;             \
        __builtin_amdgcn_global_load_lds(                                            \
            (const __attribute__((address_space(1))) void*)vsrc,                     \
            (__attribute__((address_space(3))) void*)&Vs[cbuf][wid*8][0],            \
            16, 0, 0);                                                               \
      } }

    for (int half = 0; half < 2; ++half) {
        const int qt = half ? (7 - jp) : jp;
        const int q0 = qt * 256 + wid * 16;   // this wave's 16 q rows
        const int kv_end = q0 + 16;           // per-wave causal bound
        const int NT = qt * 4 + 4;            // KV tiles for this block-half

        const bf16* Qp = Q + ((size_t)(b * NH_ + h) * T_ + q0) * HD_;
        bf16x8 qf[4];
#pragma unroll
        for (int c = 0; c < 4; ++c)
            qf[c] = *(const bf16x8*)&Qp[(size_t)lq * HD_ + c * 32 + lg * 8];

        f32x4 oacc[8] = {};
        float m_r = -INFINITY;
        float l_r = 0.f;

        STAGE_KV(0, 0);
        STAGE_KV(1, 1);
        asm volatile("s_waitcnt vmcnt(2)" ::: "memory");   // tile 0 landed
        __builtin_amdgcn_s_barrier();

        for (int t = 0; t < NT; ++t) {
            const int cb = t & 1;
            const int t0 = t * 64;

            if (t0 < kv_end) {   // wave-uniform predicate; barriers stay outside
                // ---- S^T = K @ Q^T (K from LDS, swizzled read) ----
                f32x4 st[4] = {};
#pragma unroll
                for (int n = 0; n < 4; ++n) {
                    bf16x8 kf[4];
#pragma unroll
                    for (int c = 0; c < 4; ++c)
                        kf[c] = *(const bf16x8*)((const char*)&Ks[cb][n*16 + lq][0]
                                                  + (((c*4 + lg) ^ lq) << 4));
                    __builtin_amdgcn_s_setprio(1);
#pragma unroll
                    for (int c = 0; c < 4; ++c)
                        st[n] = mfma16(kf[c], qf[c], st[n]);
                    __builtin_amdgcn_s_setprio(0);
                }

                // ---- causal mask (swapped layout) ----
                const int qq = q0 + lq;
#pragma unroll
                for (int n = 0; n < 4; ++n)
#pragma unroll
                    for (int r = 0; r < 4; ++r) {
                        int kk = t0 + n*16 + lg*4 + r;
                        if (kk > qq) st[n][r] = -INFINITY;
                    }

                // ---- row max (15 in-reg + 2 shfl) ----
                float rmax = st[0][0];
#pragma unroll
                for (int n = 0; n < 4; ++n)
#pragma unroll
                    for (int r = 0; r < 4; ++r) rmax = fmaxf(rmax, st[n][r]);
                rmax = fmaxf(rmax, __shfl_xor(rmax, 16));
                rmax = fmaxf(rmax, __shfl_xor(rmax, 32));

                // ---- defer-max (THR = 8 nats, log2 domain) ----
                if (__any(rmax - m_r > THR_L2)) {
                    float mnew = fmaxf(m_r, rmax);
                    float alpha = exp2f(m_r - mnew);   // first tile: exp2(-inf)=0
                    m_r = mnew;
                    l_r *= alpha;
#pragma unroll
                    for (int r = 0; r < 4; ++r) {
                        float a_pv = __shfl(alpha, lg*4 + r);   // to PV layout
#pragma unroll
                        for (int f = 0; f < 8; ++f) oacc[f][r] *= a_pv;
                    }
                }

                // ---- exp2 + row sum ----
                float rsum = 0.f;
#pragma unroll
                for (int n = 0; n < 4; ++n)
#pragma unroll
                    for (int r = 0; r < 4; ++r) {
                        float p = exp2f(st[n][r] - m_r);
                        st[n][r] = p;
                        rsum += p;
                    }
                rsum += __shfl_xor(rsum, 16);
                rsum += __shfl_xor(rsum, 32);
                l_r += rsum;

                // ---- P pack -> per-wave LDS (b64 writes), rows = q ----
#pragma unroll
                for (int n = 0; n < 4; ++n) {
                    union { bf16 hh[4]; uint2 u; } pk;
#pragma unroll
                    for (int r = 0; r < 4; ++r) pk.hh[r] = __float2bfloat16(st[n][r]);
                    *(uint2*)&p_lds[wid][lq][n*16 + lg*4] = pk.u;
                }

                // ---- O += P @ V (V from LDS, swizzled read; ks=0 then ks=1) ----
#pragma unroll
                for (int ks = 0; ks < 2; ++ks) {
                    bf16x8 pa = *(const bf16x8*)&p_lds[wid][lq][ks*32 + lg*8];
                    bf16x8 vf[8];
#pragma unroll
                    for (int f = 0; f < 8; ++f)
                        vf[f] = *(const bf16x8*)((const char*)&Vs[cb][f*16 + lq][0]
                                                  + (((ks*4 + lg) ^ (lq & 7)) << 4));
                    __builtin_amdgcn_s_setprio(1);
#pragma unroll
                    for (int f = 0; f < 8; ++f)
                        oacc[f] = mfma16(pa, vf[f], oacc[f]);
                    __builtin_amdgcn_s_setprio(0);
                }
            }

            // ---- pipeline maintenance (uniform; raw barriers + counted vmcnt) ----
            __builtin_amdgcn_s_barrier();          // all waves done reading buf[cb]
            if (t + 2 < NT) {
                STAGE_KV(cb, t + 2);               // refill freed buffer (2 loads)
                asm volatile("s_waitcnt vmcnt(2)" ::: "memory");   // own t+1 landed
            } else {
                asm volatile("s_waitcnt vmcnt(0)" ::: "memory");
            }
            __builtin_amdgcn_s_barrier();          // tile t+1 visible to all
        }

        // ---- epilogue: 1/l broadcast to PV layout, store [B,T,NH,HD] ----
        {
            float rinv = __builtin_amdgcn_rcpf(l_r);
#pragma unroll
            for (int r = 0; r < 4; ++r) {
                float rl = __shfl(rinv, lg*4 + r);
                int row = q0 + lg*4 + r;
#pragma unroll
                for (int f = 0; f < 8; ++f) {
                    int d = f*16 + lq;
                    O[((size_t)(b * T_ + row) * NH_ + h) * HD_ + d] =
                        __float2bfloat16(oacc[f][r] * rl);
                }
            }
        }
    }
#undef STAGE_KV
}

// ---------------- launch ----------------
extern "C" void kernel_launch(void* const* d_in, const int* in_sizes, int n_in,
                              void* d_out, int out_size, void* d_ws, size_t ws_size,
                              hipStream_t stream) {
    const float* x  = (const float*)d_in[0];
    const float* wq = (const float*)d_in[1];
    const float* wk = (const float*)d_in[2];
    const float* wv = (const float*)d_in[3];
    const float* wo = (const float*)d_in[4];
    float* out = (float*)d_out;

    bf16* ws    = (bf16*)d_ws;
    bf16* xb    = ws;
    bf16* wqkvT = xb + (size_t)M_ * C_;
    bf16* qr_wo = wqkvT + (size_t)QKVN_ * C_;
    bf16* region = qr_wo + (size_t)C_ * C_;
    bf16* k_r  = region;
    bf16* vt   = k_r + (size_t)B_ * NKV_ * T_ * HD_;
    bf16* vbuf = vt  + (size_t)B_ * NKV_ * T_ * HD_;
    float2* tab = (float2*)(vbuf + (size_t)B_ * T_ * NKV_ * HD_);

    bf16* attn = xb;      // fattn output (xb dead as A after the gemms)

    // 1) merged prep: cast x | transpose wq,wk,wv | rope table (one dispatch)
    prep_all<<<dim3(16384 + 24576 + 512), 256, 0, stream>>>(x, wq, wk, wv, xb, wqkvT, tab);

    // 2) merged QKV GEMM (256 blocks: 1.0x Q-tile + 0.5x KV-tile each)
    gemm_qkv_all<<<dim3(256), 512, 0, stream>>>(
        xb, wqkvT, qr_wo, k_r, vbuf, tab, M_, C_);

    // 3) V transpose
    vtrans<<<B_ * NKV_ * (T_ / 32) * (HD_ / 32), 256, 0, stream>>>(vbuf, vt);

    // 4) attention (256 blocks x 1024 threads)
    fattn<<<dim3(256), 1024, 0, stream>>>(qr_wo, k_r, vt, attn);

    // 5) wo transpose into freed q_r region, then output projection
    transpose_cast<<<dim3(128, 128), 256, 0, stream>>>(wo, qr_wo, NH_ * HD_, C_);
    gemm256<float><<<dim3((C_ / 256) * (M_ / 256)), 512, 0, stream>>>(attn, qr_wo, out, M_, C_, C_);
}